// Round 3
// baseline (1211.894 us; speedup 1.0000x reference)
//
#include <hip/hip_runtime.h>
#include <hip/hip_bf16.h>

#define B_ 1024
#define L_ 2048
#define C_ 32
#define O_ 2048

typedef short bf16x8 __attribute__((ext_vector_type(8)));
typedef float f32x4 __attribute__((ext_vector_type(4)));

__device__ __forceinline__ unsigned int f2bf(float f) {
    union { float f; unsigned int u; } v; v.f = f;
    unsigned int r = v.u + (0x7fffu + ((v.u >> 16) & 1u));
    return r >> 16;
}

__device__ __forceinline__ void async16(const void* g, const void* l) {
    __builtin_amdgcn_global_load_lds(
        (const __attribute__((address_space(1))) unsigned int*)g,
        (__attribute__((address_space(3))) unsigned int*)l, 16, 0, 0);
}

// ---------------- tiny pre-pass: W_pos fp32 -> bf16 ----------------
__global__ __launch_bounds__(256) void k_wpcvt(const float* __restrict__ wp,
                                               unsigned short* __restrict__ wpb) {
    const size_t i = ((size_t)blockIdx.x * 256 + threadIdx.x) * 8;
    float4 v0 = *(const float4*)(wp + i);
    float4 v1 = *(const float4*)(wp + i + 4);
    uint4 q;
    q.x = f2bf(v0.x) | (f2bf(v0.y) << 16);
    q.y = f2bf(v0.z) | (f2bf(v0.w) << 16);
    q.z = f2bf(v1.x) | (f2bf(v1.y) << 16);
    q.w = f2bf(v1.z) | (f2bf(v1.w) << 16);
    *(uint4*)(wpb + i) = q;
}

// ---------------- fused GEMM: A staged directly from x (fp32->bf16 transpose in staging) ----------------
// math: u[(b,c), o] = sum_l x[b,l,c] * Wp[o,l];  out[b,o] = sum_c Wc[o,c] * u[(b,c),o]
// M rows r = b_local*32 + c (per mt: 8 b's), N = o, K = l. 256x256 tile, BK=64, 8 waves.
// LDS A half h = channels [16h,16h+16) of all 8 b's; local row l_r = b_local*16 + (c&15).
// kgroup swizzle key = row&7 on both sides (proven 0-conflict on reads).
// One barrier per K-tile; all staging issued early; compiler emits counted waits.

#define SPIN() __builtin_amdgcn_sched_barrier(0)
#define PRIO1() __builtin_amdgcn_s_setprio(1)
#define PRIO0() __builtin_amdgcn_s_setprio(0)

#define STGB(tgt, tk) do { \
    _Pragma("unroll") for (int h_ = 0; h_ < 2; ++h_) { \
        const unsigned short* gp_ = Wp + offB + (size_t)(tk) * 64 + h_ * 32768; \
        char* lp_ = (char*)Bs + (tgt) * 32768 + h_ * 16384 + stgo; \
        async16(gp_, lp_); \
        async16(gp_ + 16384, lp_ + 1024); } } while (0)

#define ALOAD(tk) do { \
    const float* xo_ = xth + (size_t)(tk) * 2048; \
    _Pragma("unroll") for (int j_ = 0; j_ < 2; ++j_) \
    _Pragma("unroll") for (int r_ = 0; r_ < 4; ++r_) \
        sr[j_ * 4 + r_] = *(const f32x4*)(xo_ + j_ * 1024 + r_ * 32); } while (0)

#define AWRITE(tgt) do { \
    _Pragma("unroll") for (int j_ = 0; j_ < 2; ++j_) { \
        const int lq_ = j_ * 8 + g3; \
        _Pragma("unroll") for (int k_ = 0; k_ < 4; ++k_) { \
            const int c_ = cq * 4 + k_; \
            const int lr_ = (w << 4) + (c_ & 15); \
            char* ad_ = (char*)As + (tgt) * 32768 + (c_ >> 4) * 16384 + lr_ * 128 \
                        + (((lq_ >> 1) ^ (lr_ & 7)) << 4) + ((lq_ & 1) << 3); \
            uint2 dw_; \
            dw_.x = f2bf(sr[j_ * 4 + 0][k_]) | (f2bf(sr[j_ * 4 + 1][k_]) << 16); \
            dw_.y = f2bf(sr[j_ * 4 + 2][k_]) | (f2bf(sr[j_ * 4 + 3][k_]) << 16); \
            *(uint2*)ad_ = dw_; } } } while (0)

#define RD_A(buf, am, dst) do { \
    _Pragma("unroll") for (int p_ = 0; p_ < 4; ++p_) { \
        const char* ap_ = (const char*)As + (buf) * 32768 + (am) * 16384 + rowA[p_]; \
        dst[p_][0] = *(const bf16x8*)(ap_ + kof0); \
        dst[p_][1] = *(const bf16x8*)(ap_ + kof1); } } while (0)

#define RD_B(buf, bn, dst) do { \
    _Pragma("unroll") for (int q_ = 0; q_ < 2; ++q_) { \
        const char* bp_ = (const char*)Bs + (buf) * 32768 + (bn) * 16384 + rowB[q_]; \
        dst[q_][0] = *(const bf16x8*)(bp_ + kof0); \
        dst[q_][1] = *(const bf16x8*)(bp_ + kof1); } } while (0)

#define MMX(asrc, am, bn, bsrc) do { \
    _Pragma("unroll") for (int p_ = 0; p_ < 4; ++p_) \
    _Pragma("unroll") for (int q_ = 0; q_ < 2; ++q_) \
    _Pragma("unroll") for (int ks_ = 0; ks_ < 2; ++ks_) \
        acc[2 * p_ + (am)][2 * q_ + (bn)] = __builtin_amdgcn_mfma_f32_16x16x32_bf16( \
            asrc[p_][ks_], bsrc[q_][ks_], acc[2 * p_ + (am)][2 * q_ + (bn)], 0, 0, 0); } while (0)

// KSTEP(buf, T): compute tile T from buf; stage tile tn=min(T+1,31) into buf^1.
#define KSTEP(buf, T) do { \
    const int tn_ = (T) < 31 ? (T) + 1 : 31; \
    /* ph0: burst reads + all staging issues */ \
    RD_A(buf, 0, afa); RD_B(buf, 0, bfe); RD_B(buf, 1, bfo); \
    ALOAD(tn_); \
    STGB(buf ^ 1, tn_); \
    SPIN(); \
    PRIO1(); MMX(afa, 0, 0, bfe); PRIO0(); SPIN(); \
    /* ph1: prefetch af half 1 while computing Q01 */ \
    RD_A(buf, 1, afb); SPIN(); \
    PRIO1(); MMX(afa, 0, 1, bfo); PRIO0(); SPIN(); \
    /* ph2: convert + LDS-write next A tile (vmcnt auto-waited), then Q10 */ \
    AWRITE(buf ^ 1); SPIN(); \
    PRIO1(); MMX(afb, 1, 0, bfe); PRIO0(); SPIN(); \
    /* ph3: Q11, then the tile's single full-drain barrier */ \
    PRIO1(); MMX(afb, 1, 1, bfo); PRIO0(); \
    __syncthreads(); \
} while (0)

__global__ __launch_bounds__(512, 2) void k_gemm(const float* __restrict__ x,
                                                 const unsigned short* __restrict__ Wp,
                                                 const float* __restrict__ Wc,
                                                 float* __restrict__ out) {
    __shared__ unsigned short As[2][2][8192];   // [buf][half][128 rows x 64 k]
    __shared__ unsigned short Bs[2][2][8192];
    const int blk = blockIdx.x;
    // XCD-grouping: 8 blocks sharing mt (same x-panel) keep the same (blk&7) -> same XCD.
    const int nt = (blk >> 3) & 7;
    const int mt = ((blk >> 6) << 3) | (blk & 7);
    const int t = threadIdx.x, lane = t & 63, w = t >> 6;
    const int wm = w >> 2, wn = w & 3;
    const int quad = lane >> 4, c16 = lane & 15;

    // B staging (global_load_lds, linear dest, source-swizzled)
    const int s_ = lane >> 3, kg = lane & 7;
    const int kgs = (kg ^ s_) << 3;
    const size_t offB = (size_t)((nt << 8) + (w << 5) + s_) * 2048 + kgs;
    const int stgo = w << 11;

    // A staging (reg-staged from x fp32): wave w owns b_local = w
    const int cq = lane & 7, g3 = lane >> 3;
    const float* xth = x + (size_t)((mt << 3) + w) * 65536 + g3 * 128 + cq * 4;

    // fragment read addressing
    int rowA[4], rowB[2];
#pragma unroll
    for (int p = 0; p < 4; ++p) rowA[p] = ((((wm << 2) + p) << 4) | c16) << 7;
#pragma unroll
    for (int q = 0; q < 2; ++q) rowB[q] = ((((wn << 1) + q) << 4) | c16) << 7;
    const int sw = c16 & 7;
    const int kof0 = (quad ^ sw) << 4;
    const int kof1 = ((4 + quad) ^ sw) << 4;

    bf16x8 afa[4][2], afb[4][2], bfe[2][2], bfo[2][2];
    f32x4 sr[8];
    f32x4 acc[8][4] = {};

    // prologue: stage tile 0 into buf0
    ALOAD(0);
    STGB(0, 0);
    AWRITE(0);
    __syncthreads();

    for (int I = 0; I < 32; I += 2) {
        KSTEP(0, I);
        KSTEP(1, I + 1);
    }

    // ---- epilogue: weighted c-reduction, out[b,o] = sum_c Wc[o,c]*u[(b,c),o] ----
    // acc row (2p+am): b = mt*8 + wm*4 + p, c = am*16 + quad*4 + reg
    const int colW = (nt << 8) + (wn << 6);
#pragma unroll
    for (int p = 0; p < 4; ++p) {
        const int bg = (mt << 3) + (wm << 2) + p;
#pragma unroll
        for (int ni = 0; ni < 4; ++ni) {
            const int o = colW + (ni << 4) + c16;
            const f32x4 w0 = *(const f32x4*)(Wc + o * 32 + quad * 4);
            const f32x4 w1 = *(const f32x4*)(Wc + o * 32 + 16 + quad * 4);
            const f32x4 aA = acc[2 * p][ni];
            const f32x4 aB = acc[2 * p + 1][ni];
            float sv = aA[0] * w0[0] + aA[1] * w0[1] + aA[2] * w0[2] + aA[3] * w0[3]
                     + aB[0] * w1[0] + aB[1] * w1[1] + aB[2] * w1[2] + aB[3] * w1[3];
            sv += __shfl_xor(sv, 16, 64);
            sv += __shfl_xor(sv, 32, 64);
            if (quad == 0) out[(size_t)bg * O_ + o] = sv;
        }
    }
}

// ---------------- fallback (only if ws too small): fp32 VALU, slow but correct ----------------
__global__ __launch_bounds__(256) void k_fallback(const float* __restrict__ x,
                                                  const float* __restrict__ wpos,
                                                  const float* __restrict__ wchan,
                                                  float* __restrict__ out) {
    __shared__ float xs[128 * 32];
    const int b = blockIdx.x >> 3;
    const int o = ((blockIdx.x & 7) << 8) + threadIdx.x;
    float wc[32];
#pragma unroll
    for (int c = 0; c < 32; ++c) wc[c] = wchan[o * 32 + c];
    float acc = 0.f;
    for (int l0 = 0; l0 < 2048; l0 += 128) {
        __syncthreads();
#pragma unroll
        for (int i = 0; i < 16; ++i) {
            int f = i * 256 + threadIdx.x;
            xs[f] = x[(size_t)b * 65536 + (size_t)l0 * 32 + f];
        }
        __syncthreads();
        for (int l = 0; l < 128; ++l) {
            float wp = wpos[(size_t)o * 2048 + l0 + l];
            float s = 0.f;
#pragma unroll
            for (int c = 0; c < 32; ++c) s += xs[l * 32 + c] * wc[c];
            acc += wp * s;
        }
    }
    out[(size_t)b * 2048 + o] = acc;
}

extern "C" void kernel_launch(void* const* d_in, const int* in_sizes, int n_in,
                              void* d_out, int out_size, void* d_ws, size_t ws_size,
                              hipStream_t stream) {
    const float* x     = (const float*)d_in[0];
    const float* wpos  = (const float*)d_in[1];
    const float* wchan = (const float*)d_in[2];
    float* out = (float*)d_out;

    const size_t wp_bytes = (size_t)O_ * L_ * 2;        // 8 MiB

    if (ws_size >= wp_bytes) {
        unsigned short* wpb = (unsigned short*)d_ws;
        k_wpcvt<<<2048, 256, 0, stream>>>(wpos, wpb);
        k_gemm<<<(B_ * C_ / 256) * (O_ / 256), 512, 0, stream>>>(x, wpb, wchan, out);
    } else {
        k_fallback<<<B_ * 8, 256, 0, stream>>>(x, wpos, wchan, out);
    }
}

// Round 4
// 615.629 us; speedup vs baseline: 1.9685x; 1.9685x over previous
//
#include <hip/hip_runtime.h>
#include <hip/hip_bf16.h>

#define B_ 1024
#define L_ 2048
#define C_ 32
#define O_ 2048

typedef short bf16x8 __attribute__((ext_vector_type(8)));
typedef float f32x4 __attribute__((ext_vector_type(4)));

__device__ __forceinline__ unsigned int f2bf(float f) {
    union { float f; unsigned int u; } v; v.f = f;
    unsigned int r = v.u + (0x7fffu + ((v.u >> 16) & 1u));
    return r >> 16;
}

__device__ __forceinline__ void async16(const void* g, const void* l) {
    __builtin_amdgcn_global_load_lds(
        (const __attribute__((address_space(1))) unsigned int*)g,
        (__attribute__((address_space(3))) unsigned int*)l, 16, 0, 0);
}

// ---------------- fused pre-pass ----------------
// blocks [0, 8192):   x (B,L,C) fp32 -> xT (B,C,L) bf16, LDS-staged coalesced transpose
// blocks [8192, 10240): W_pos fp32 -> bf16
__global__ __launch_bounds__(256) void k_prep(const float* __restrict__ x,
                                              unsigned short* __restrict__ xT,
                                              const float* __restrict__ wp,
                                              unsigned short* __restrict__ wpb) {
    const int t = threadIdx.x;
    if (blockIdx.x < 8192) {
        __shared__ unsigned int lds[32 * 128];
        const int b  = blockIdx.x >> 3;
        const int l0 = (blockIdx.x & 7) << 8;        // 256-l chunk
        const int c0 = (t & 7) << 2;                 // channel quad 0,4,..,28
        const int lr = (t >> 3) << 1;                // even l within 64-l group
        const float* src = x + (size_t)b * (L_ * C_) + (size_t)l0 * C_;
#pragma unroll
        for (int i = 0; i < 4; ++i) {
            const int l = i * 64 + lr;
            const float4 e = *(const float4*)(src + (size_t)l * C_ + c0);
            const float4 o = *(const float4*)(src + (size_t)(l + 1) * C_ + c0);
            const int dcol = l >> 1;
            const float ef[4] = {e.x, e.y, e.z, e.w};
            const float of[4] = {o.x, o.y, o.z, o.w};
#pragma unroll
            for (int j = 0; j < 4; ++j) {
                const int c = c0 + j;
                const unsigned int pk = f2bf(ef[j]) | (f2bf(of[j]) << 16);
                lds[c * 128 + (dcol ^ (((c >> 2) & 7) << 2))] = pk;
            }
        }
        __syncthreads();
        unsigned short* dst = xT + (size_t)b * (C_ * L_) + l0;
#pragma unroll
        for (int i = 0; i < 4; ++i) {
            const int f  = i * 256 + t;
            const int c  = f >> 5;
            const int lq = f & 31;
            const int k  = (c >> 2) & 7;
            const unsigned int* s = &lds[c * 128 + ((lq ^ k) << 2)];
            uint4 q; q.x = s[0]; q.y = s[1]; q.z = s[2]; q.w = s[3];
            *(uint4*)(dst + (size_t)c * L_ + lq * 8) = q;
        }
    } else {
        const size_t i = ((size_t)(blockIdx.x - 8192) * 256 + t) * 8;
        float4 v0 = *(const float4*)(wp + i);
        float4 v1 = *(const float4*)(wp + i + 4);
        uint4 q;
        q.x = f2bf(v0.x) | (f2bf(v0.y) << 16);
        q.y = f2bf(v0.z) | (f2bf(v0.w) << 16);
        q.z = f2bf(v1.x) | (f2bf(v1.y) << 16);
        q.w = f2bf(v1.z) | (f2bf(v1.w) << 16);
        *(uint4*)(wpb + i) = q;
    }
}

// ---------------- main GEMM: 256x256, BK=64, 1 barrier/tile, counted-lgkm read-ahead ----------------
// A = xT (32768 x 2048 bf16, rows r = b*32+c), B^T = Wp (2048 x 2048 bf16).
// Quadrants: Q00(afa,bfe) Q01(afa,bfo) Q10(afb,bfe) Q11(afb,bfo).
// Per tile T (data in buf=T&1):
//   ph0: stage T+1 -> buf^1 (safe: buf^1 reads drained at T-1's lgkm(0) + boundary BAR);
//        issue bfo(4); lgkm(4) [waits boundary afa+bfe(12)]; MM Q00
//   ph1: issue afb(8); lgkm(8) [waits bfo]; MM Q01
//   ph2: lgkm(0) [drains afb + everything]; MM Q10
//   ph3: MM Q11; vmcnt(0) [T+1 staged]; BAR; read afa+bfe of T+1 from buf^1
// 1 s_barrier + 1 vmcnt(0) per tile; ds data-return overlaps MFMA via counted lgkm.

#define BAR() __builtin_amdgcn_s_barrier()
#define SPIN() __builtin_amdgcn_sched_barrier(0)
#define LGKM(N) do { asm volatile("s_waitcnt lgkmcnt(" #N ")" ::: "memory"); __builtin_amdgcn_sched_barrier(0); } while (0)
#define VMW(N) asm volatile("s_waitcnt vmcnt(" #N ")" ::: "memory")
#define PRIO1() __builtin_amdgcn_s_setprio(1)
#define PRIO0() __builtin_amdgcn_s_setprio(0)

#define STG_A(buf, h, tk) do { \
    async16(A + offA + (size_t)(tk) * 64 + (h) * 32768,         (char*)As + (buf) * 32768 + (h) * 16384 + stgo); \
    async16(A + offA + (size_t)(tk) * 64 + (h) * 32768 + 16384, (char*)As + (buf) * 32768 + (h) * 16384 + stgo + 1024); } while (0)
#define STG_B(buf, h, tk) do { \
    async16(Wp + offB + (size_t)(tk) * 64 + (h) * 32768,         (char*)Bs + (buf) * 32768 + (h) * 16384 + stgo); \
    async16(Wp + offB + (size_t)(tk) * 64 + (h) * 32768 + 16384, (char*)Bs + (buf) * 32768 + (h) * 16384 + stgo + 1024); } while (0)
#define STG_T(tgt, tk) do { STG_A(tgt, 0, tk); STG_A(tgt, 1, tk); STG_B(tgt, 0, tk); STG_B(tgt, 1, tk); } while (0)

#define RD_A(buf, am, dst) do { \
    _Pragma("unroll") for (int p_ = 0; p_ < 4; ++p_) { \
        const char* ap_ = (const char*)As + (buf) * 32768 + (am) * 16384 + rowA[p_]; \
        dst[p_][0] = *(const bf16x8*)(ap_ + kof0); \
        dst[p_][1] = *(const bf16x8*)(ap_ + kof1); } } while (0)
#define RD_B(buf, bn, dst) do { \
    _Pragma("unroll") for (int q_ = 0; q_ < 2; ++q_) { \
        const char* bp_ = (const char*)Bs + (buf) * 32768 + (bn) * 16384 + rowB[q_]; \
        dst[q_][0] = *(const bf16x8*)(bp_ + kof0); \
        dst[q_][1] = *(const bf16x8*)(bp_ + kof1); } } while (0)

#define MMX(asrc, am, bn, bsrc) do { \
    _Pragma("unroll") for (int p_ = 0; p_ < 4; ++p_) \
    _Pragma("unroll") for (int q_ = 0; q_ < 2; ++q_) \
    _Pragma("unroll") for (int ks_ = 0; ks_ < 2; ++ks_) \
        acc[2 * p_ + (am)][2 * q_ + (bn)] = __builtin_amdgcn_mfma_f32_16x16x32_bf16( \
            asrc[p_][ks_], bsrc[q_][ks_], acc[2 * p_ + (am)][2 * q_ + (bn)], 0, 0, 0); } while (0)

#define STEP(buf, T) do { \
    STG_T((buf) ^ 1, (T) + 1); \
    RD_B(buf, 1, bfo); \
    LGKM(4); \
    PRIO1(); MMX(afa, 0, 0, bfe); PRIO0(); SPIN(); \
    RD_A(buf, 1, afb); \
    LGKM(8); \
    PRIO1(); MMX(afa, 0, 1, bfo); PRIO0(); SPIN(); \
    LGKM(0); \
    PRIO1(); MMX(afb, 1, 0, bfe); PRIO0(); SPIN(); \
    PRIO1(); MMX(afb, 1, 1, bfo); PRIO0(); SPIN(); \
    VMW(0); BAR(); \
    RD_A((buf) ^ 1, 0, afa); RD_B((buf) ^ 1, 0, bfe); \
} while (0)

__global__ __launch_bounds__(512, 2) void k_gemm(const unsigned short* __restrict__ A,
                                                 const unsigned short* __restrict__ Wp,
                                                 const float* __restrict__ Wc,
                                                 float* __restrict__ out) {
    __shared__ unsigned short As[2][2][8192];   // [buf][16-row-block-parity half][128 x 64]
    __shared__ unsigned short Bs[2][2][8192];
    const int blk = blockIdx.x;
    // XCD grouping (grid 1024 % 8 == 0, bijective): the 8 nt-blocks of one mt share an XCD
    const int nt = (blk >> 3) & 7;
    const int mt = ((blk >> 6) << 3) | (blk & 7);
    const int t = threadIdx.x, lane = t & 63, w = t >> 6;
    const int wm = w >> 2, wn = w & 3;
    const int quad = lane >> 4, c16 = lane & 15;

    const int s_ = lane >> 3, kg = lane & 7;
    const int kgs = (kg ^ s_) << 3;
    const size_t offA = (size_t)((mt << 8) + (w << 5) + s_) * 2048 + kgs;
    const size_t offB = (size_t)((nt << 8) + (w << 5) + s_) * 2048 + kgs;
    const int stgo = w << 11;

    int rowA[4], rowB[2];
#pragma unroll
    for (int p = 0; p < 4; ++p) rowA[p] = ((((wm << 2) + p) << 4) | c16) << 7;
#pragma unroll
    for (int q = 0; q < 2; ++q) rowB[q] = ((((wn << 1) + q) << 4) | c16) << 7;
    const int sw = c16 & 7;
    const int kof0 = (quad ^ sw) << 4;
    const int kof1 = ((4 + quad) ^ sw) << 4;

    bf16x8 afa[4][2], afb[4][2], bfe[2][2], bfo[2][2];
    f32x4 acc[8][4] = {};

    // prologue: stage tile 0 -> buf0, drain, pre-read Q00 fragments
    STG_T(0, 0);
    VMW(0); BAR();
    RD_A(0, 0, afa); RD_B(0, 0, bfe);

    for (int I = 0; I < 15; ++I) {
        STEP(0, 2 * I);
        STEP(1, 2 * I + 1);
    }
    STEP(0, 30);            // stages tile 31 -> buf1; boundary pre-reads tile-31 frags

    // tail: tile 31 (buf1), no staging, no boundary
    RD_B(1, 1, bfo);
    LGKM(4);
    PRIO1(); MMX(afa, 0, 0, bfe); PRIO0(); SPIN();
    RD_A(1, 1, afb);
    LGKM(8);
    PRIO1(); MMX(afa, 0, 1, bfo); PRIO0(); SPIN();
    LGKM(0);
    PRIO1(); MMX(afb, 1, 0, bfe); PRIO0(); SPIN();
    PRIO1(); MMX(afb, 1, 1, bfo); PRIO0();

    // ---- epilogue: weighted c-reduction, out[b,o] = sum_c Wc[o,c]*u[(b,c),o] ----
    // acc[2p+am][ni]: b = mt*8 + wm*4 + p, c = am*16 + quad*4 + reg, o = colW + ni*16 + c16
    const int colW = (nt << 8) + (wn << 6);
#pragma unroll
    for (int p = 0; p < 4; ++p) {
        const int bg = (mt << 3) + (wm << 2) + p;
#pragma unroll
        for (int ni = 0; ni < 4; ++ni) {
            const int o = colW + (ni << 4) + c16;
            const f32x4 w0 = *(const f32x4*)(Wc + o * 32 + quad * 4);
            const f32x4 w1 = *(const f32x4*)(Wc + o * 32 + 16 + quad * 4);
            const f32x4 aA = acc[2 * p][ni];
            const f32x4 aB = acc[2 * p + 1][ni];
            float sv = aA[0] * w0[0] + aA[1] * w0[1] + aA[2] * w0[2] + aA[3] * w0[3]
                     + aB[0] * w1[0] + aB[1] * w1[1] + aB[2] * w1[2] + aB[3] * w1[3];
            sv += __shfl_xor(sv, 16, 64);
            sv += __shfl_xor(sv, 32, 64);
            if (quad == 0) out[(size_t)bg * O_ + o] = sv;
        }
    }
}

// ---------------- fallback (only if ws too small): fp32 VALU, slow but correct ----------------
__global__ __launch_bounds__(256) void k_fallback(const float* __restrict__ x,
                                                  const float* __restrict__ wpos,
                                                  const float* __restrict__ wchan,
                                                  float* __restrict__ out) {
    __shared__ float xs[128 * 32];
    const int b = blockIdx.x >> 3;
    const int o = ((blockIdx.x & 7) << 8) + threadIdx.x;
    float wc[32];
#pragma unroll
    for (int c = 0; c < 32; ++c) wc[c] = wchan[o * 32 + c];
    float acc = 0.f;
    for (int l0 = 0; l0 < 2048; l0 += 128) {
        __syncthreads();
#pragma unroll
        for (int i = 0; i < 16; ++i) {
            int f = i * 256 + threadIdx.x;
            xs[f] = x[(size_t)b * 65536 + (size_t)l0 * 32 + f];
        }
        __syncthreads();
        for (int l = 0; l < 128; ++l) {
            float wp = wpos[(size_t)o * 2048 + l0 + l];
            float s = 0.f;
#pragma unroll
            for (int c = 0; c < 32; ++c) s += xs[l * 32 + c] * wc[c];
            acc += wp * s;
        }
    }
    out[(size_t)b * 2048 + o] = acc;
}

extern "C" void kernel_launch(void* const* d_in, const int* in_sizes, int n_in,
                              void* d_out, int out_size, void* d_ws, size_t ws_size,
                              hipStream_t stream) {
    const float* x     = (const float*)d_in[0];
    const float* wpos  = (const float*)d_in[1];
    const float* wchan = (const float*)d_in[2];
    float* out = (float*)d_out;

    const size_t xT_bytes = (size_t)B_ * C_ * L_ * 2;   // 128 MiB
    const size_t wp_bytes = (size_t)O_ * L_ * 2;        // 8 MiB

    if (ws_size >= xT_bytes + wp_bytes) {
        unsigned short* xT  = (unsigned short*)d_ws;
        unsigned short* wpb = (unsigned short*)((char*)d_ws + xT_bytes);
        k_prep<<<8192 + 2048, 256, 0, stream>>>(x, xT, wpos, wpb);
        k_gemm<<<(B_ * C_ / 256) * (O_ / 256), 512, 0, stream>>>(xT, wpb, wchan, out);
    } else {
        k_fallback<<<B_ * 8, 256, 0, stream>>>(x, wpos, wchan, out);
    }
}